// Round 1
// baseline (458.342 us; speedup 1.0000x reference)
//
#include <hip/hip_runtime.h>

#define EPS 1e-5f

// ---------------- K0: fold BN into weights, transpose for s_load ----------------
__global__ void k0_prep(const float* __restrict__ comp_w, const float* __restrict__ comp_b,
                        const float* __restrict__ bn1_g, const float* __restrict__ bn1_b,
                        const float* __restrict__ bn1_m, const float* __restrict__ bn1_v,
                        const float* __restrict__ enc_w, const float* __restrict__ enc_b,
                        const float* __restrict__ bn2_g, const float* __restrict__ bn2_b,
                        const float* __restrict__ bn2_m, const float* __restrict__ bn2_v,
                        float* __restrict__ W1wT, float* __restrict__ b1f,
                        float* __restrict__ encT, float* __restrict__ biasT)
{
    int tid = threadIdx.x; // 256 threads, 1 block
    for (int i = tid; i < 256 * 64; i += 256) {
        int cin = i >> 6, co = i & 63;
        float s = bn1_g[co] * rsqrtf(bn1_v[co] + EPS);
        W1wT[i] = comp_w[co * 256 + cin] * s;
    }
    if (tid < 64) {
        float s = bn1_g[tid] * rsqrtf(bn1_v[tid] + EPS);
        b1f[tid] = (comp_b[tid] - bn1_m[tid]) * s + bn1_b[tid];
    }
    for (int i = tid; i < 4 * 64 * 9 * 32; i += 256) {
        int k = i & 31;
        int rest = i >> 5;
        int dxy = rest % 9;
        int tmp = rest / 9;
        int cin = tmp & 63, p = tmp >> 6;
        float v = 0.f;
        if (k < 25) {
            int ko = 4 * k + p;
            float s = bn2_g[ko] * rsqrtf(bn2_v[ko] + EPS);
            v = enc_w[(ko * 64 + cin) * 9 + dxy] * s;
        }
        encT[i] = v;
    }
    if (tid < 4 * 32) {
        int p = tid >> 5, k = tid & 31;
        float v = 0.f;
        if (k < 25) {
            int ko = 4 * k + p;
            float s = bn2_g[ko] * rsqrtf(bn2_v[ko] + EPS);
            v = (enc_b[ko] - bn2_m[ko]) * s + bn2_b[ko];
        }
        biasT[tid] = v;
    }
}

// ---------------- K1: conv1x1 + bias + ReLU ----------------
// grid 512 = cog(4, slowest -> same-XCD shares X tile via L2) * b(8) * posTile(16)
// 2 blocks/CU, 8 waves/CU. Thread: 1 pos, 16 co accumulators, cin unroll 8 for MLP.
__global__ __launch_bounds__(256, 2) void k1_conv1(const float* __restrict__ X,
                                                   const float* __restrict__ W1wT,
                                                   const float* __restrict__ b1f,
                                                   float* __restrict__ W1)
{
    int blk = blockIdx.x;
    int cog = blk >> 7;            // 0..3
    int b   = (blk >> 4) & 7;
    int pt  = blk & 15;
    int pos = pt * 256 + threadIdx.x;
    const float* xp = X + (size_t)b * 256 * 4096 + pos;
    const float* wp = W1wT + cog * 16;      // uniform -> s_load
    float acc[16];
#pragma unroll
    for (int k = 0; k < 16; ++k) acc[k] = 0.f;
#pragma unroll 8
    for (int cin = 0; cin < 256; ++cin) {
        float x = xp[(size_t)cin * 4096];
        const float* w = wp + cin * 64;
#pragma unroll
        for (int k = 0; k < 16; ++k) acc[k] = fmaf(w[k], x, acc[k]);
    }
    float* op = W1 + ((size_t)b * 64 + cog * 16) * 4096 + pos;
#pragma unroll
    for (int k = 0; k < 16; ++k) {
        float v = acc[k] + b1f[cog * 16 + k];
        op[(size_t)k * 4096] = fmaxf(v, 0.f);
    }
}

// ---------------- K2: conv3x3 + BN + pixel-shuffle + softmax(25) ----------------
// 512 threads = 8 waves = p(4) x cinHalf(2). Halves the 576-long s_load chain and
// doubles resident waves (R2: 8 waves/CU latency-bound). Partial accs combined in LDS.
__global__ __launch_bounds__(512, 4) void k2_conv2(const float* __restrict__ W1,
                                                   const float* __restrict__ encT,
                                                   const float* __restrict__ biasT,
                                                   float* __restrict__ Wsm)
{
    __shared__ float tile[6400];    // 64 cin x 10 x 10, 25.6 KB
    __shared__ float red[6400];     // [p][lane][25] partials, 25.6 KB (stride 25 -> 2-way)
    int blk = blockIdx.x;
    int tc = blk & 7;
    int tr = (blk >> 3) & 7;
    int b  = blk >> 6;
    int tid = threadIdx.x;

    const float* wb = W1 + (size_t)b * 64 * 4096;
    for (int i = tid; i < 6400; i += 512) {
        int cin = i / 100;
        int rr = (i - cin * 100) / 10;
        int cc = i - cin * 100 - rr * 10;
        int r = tr * 8 - 1 + rr, c = tc * 8 - 1 + cc;
        float v = 0.f;
        if (r >= 0 && r < 64 && c >= 0 && c < 64) v = wb[cin * 4096 + r * 64 + c];
        tile[i] = v;
    }
    __syncthreads();

    int w    = tid >> 6;
    int p    = __builtin_amdgcn_readfirstlane(w & 3);
    int cinh = __builtin_amdgcn_readfirstlane(w >> 2);
    int lane = tid & 63;
    int pr = lane >> 3, pc = lane & 7;
    const float* wt = encT + (size_t)(p * 576 + cinh * 288) * 32;  // [p][cin][dxy][32]
    const float* tp = tile + cinh * 32 * 100;
    float acc[25];
#pragma unroll
    for (int k = 0; k < 25; ++k) acc[k] = 0.f;

    for (int cin = 0; cin < 32; ++cin) {
#pragma unroll
        for (int dy = 0; dy < 3; ++dy) {
#pragma unroll
            for (int dx = 0; dx < 3; ++dx) {
                float v = tp[cin * 100 + (pr + dy) * 10 + (pc + dx)];
                const float* wv = wt + (cin * 9 + dy * 3 + dx) * 32;  // uniform -> s_load
#pragma unroll
                for (int k = 0; k < 25; ++k) acc[k] = fmaf(wv[k], v, acc[k]);
            }
        }
    }

    if (cinh == 0) {
        float* rp = red + (p * 64 + lane) * 25;
#pragma unroll
        for (int k = 0; k < 25; ++k) rp[k] = acc[k];
    }
    __syncthreads();
    if (cinh == 1) {
        const float* rp = red + (p * 64 + lane) * 25;
#pragma unroll
        for (int k = 0; k < 25; ++k) acc[k] += rp[k];

        const float* bp = biasT + p * 32;
        float mx = -1e30f;
#pragma unroll
        for (int k = 0; k < 25; ++k) { acc[k] += bp[k]; mx = fmaxf(mx, acc[k]); }
        float sum = 0.f;
#pragma unroll
        for (int k = 0; k < 25; ++k) { acc[k] = __expf(acc[k] - mx); sum += acc[k]; }
        float rs = 1.f / sum;
#pragma unroll
        for (int k = 0; k < 25; ++k) acc[k] *= rs;

        int py = p >> 1, px = p & 1;
        int y = (tr * 8 + pr) * 2 + py, x = (tc * 8 + pc) * 2 + px;
        float* op = Wsm + (((size_t)b * 128 + y) * 128 + x) * 28;
#pragma unroll
        for (int k = 0; k < 6; ++k) {
            float4 v = make_float4(acc[k*4], acc[k*4+1], acc[k*4+2], acc[k*4+3]);
            *(float4*)(op + k * 4) = v;
        }
        op[24] = acc[24];
    }
}

// ---------------- K3: bilinear parity planes + 5x5 weighted reassembly ----------------
// R-new: phase 3 remapped — thread owns 4 x-adjacent same-parity pixels x 4 channels.
// An 8-float row window (2 aligned b128) feeds 4 pixels x 5 exact taps = 20 FMA, so
// ds_read_b128 drops 160->40/thread and FMA 640->400 (no zero-padded wsh shift).
// P strides: c-stride 148 (20*cg mod 32 -> banks {0,8,20,28} across the c-quad),
// plane 2376 (p3 -> {0,8,16,24}) — no 4-way conflicts. 100 weight VGPRs loaded
// before the barrier (in flight across the drain); ~150 VGPR < 168 cap @ 3 waves/SIMD.
#define LOADW(W, q) do { \
    float4 t0 = *(const float4*)(q);       float4 t1 = *(const float4*)((q) + 4);  \
    float4 t2 = *(const float4*)((q) + 8); float4 t3 = *(const float4*)((q) + 12); \
    float4 t4 = *(const float4*)((q) + 16); float4 t5 = *(const float4*)((q) + 20); \
    W[0]=t0.x; W[1]=t0.y; W[2]=t0.z; W[3]=t0.w; \
    W[4]=t1.x; W[5]=t1.y; W[6]=t1.z; W[7]=t1.w; \
    W[8]=t2.x; W[9]=t2.y; W[10]=t2.z; W[11]=t2.w; \
    W[12]=t3.x; W[13]=t3.y; W[14]=t3.z; W[15]=t3.w; \
    W[16]=t4.x; W[17]=t4.y; W[18]=t4.z; W[19]=t4.w; \
    W[20]=t5.x; W[21]=t5.y; W[22]=t5.z; W[23]=t5.w; \
    W[24]=(q)[24]; } while (0)

__global__ __launch_bounds__(256, 3) void k3_carafe(const float* __restrict__ X,
                                                    const float* __restrict__ Wsm,
                                                    float* __restrict__ out)
{
    __shared__ __align__(16) float Bx[16 * 236];   // 15.1 KB
    __shared__ __align__(16) float P[4 * 2376];    // 38.0 KB

    int blk = blockIdx.x;
    int chunk = blk >> 9;           // slowest: all CUs on same chunk; tile-sharers same XCD
    int b     = (blk >> 6) & 7;
    int tile  = blk & 63;
    int G0 = (tile >> 3) * 8;
    int H0 = (tile & 7) * 8;
    int c0 = chunk * 16;
    int tid = threadIdx.x;

    // phase 1: X tile [c][14][14] in 16-wide rows, clamp folded (== jax resize edges)
    {
        const float* xb = X + (size_t)(b * 256 + c0) * 4096;
        for (int i = tid; i < 16 * 196; i += 256) {
            int c = i / 196;
            int r = (i - c * 196) / 14;
            int s = i - c * 196 - r * 14;
            int gr = G0 - 3 + r; gr = gr < 0 ? 0 : (gr > 63 ? 63 : gr);
            int gc = H0 - 3 + s; gc = gc < 0 ? 0 : (gc > 63 ? 63 : gc);
            Bx[c * 236 + r * 16 + s] = xb[(size_t)c * 4096 + gr * 64 + gc];
        }
    }
    __syncthreads();

    // phase 2: parity-plane rows; lane map c=(tid>>2)&15, tl=tid&3 -> write residues
    // spread over banks (20*c2 + 12*tl mod 32). pp wave-uniform (no divergence).
    {
        int c2 = (tid >> 2) & 15;
        int tl = tid & 3;
        int pp = __builtin_amdgcn_readfirstlane(tid >> 6);
        int py2 = pp >> 1, px2 = pp & 1;
        float wy0 = py2 ? 0.75f : 0.25f, wy1 = 1.f - wy0;
        float wx0 = px2 ? 0.75f : 0.25f, wx1 = 1.f - wx0;
#pragma unroll
        for (int k = 0; k < 3; ++k) {
            int t = tl + 4 * k;
            bool row_ok = (unsigned)(G0 - 2 + t) < 64u;
            const float* rp0 = Bx + c2 * 236 + (t + py2) * 16;
            float x0[16], x1[16];
#pragma unroll
            for (int q = 0; q < 4; ++q) {
                float4 a = *(const float4*)(rp0 + q * 4);
                float4 e = *(const float4*)(rp0 + 16 + q * 4);
                x0[q*4+0]=a.x; x0[q*4+1]=a.y; x0[q*4+2]=a.z; x0[q*4+3]=a.w;
                x1[q*4+0]=e.x; x1[q*4+1]=e.y; x1[q*4+2]=e.z; x1[q*4+3]=e.w;
            }
            float v[12];
            if (px2 == 0) {
#pragma unroll
                for (int s = 0; s < 12; ++s)
                    v[s] = wy0 * (wx0 * x0[s] + wx1 * x0[s+1]) + wy1 * (wx0 * x1[s] + wx1 * x1[s+1]);
            } else {
#pragma unroll
                for (int s = 0; s < 12; ++s)
                    v[s] = wy0 * (wx0 * x0[s+1] + wx1 * x0[s+2]) + wy1 * (wx0 * x1[s+1] + wx1 * x1[s+2]);
            }
#pragma unroll
            for (int s = 0; s < 12; ++s) {
                bool ok = row_ok && ((unsigned)(H0 - 2 + s) < 64u);
                v[s] = ok ? v[s] : 0.f;
            }
            float* dst = P + pp * 2376 + c2 * 148 + t * 12;
#pragma unroll
            for (int q = 0; q < 3; ++q)
                *(float4*)(dst + q * 4) = make_float4(v[q*4], v[q*4+1], v[q*4+2], v[q*4+3]);
        }
    }

    // thread -> 4 output pixels (same row/parity, tx group of 4) x 4 channels
    int cg  = tid & 3;              // channel group: c = cg + 4*i (20*c mod 32 spreads banks)
    int gid = tid >> 2;
    int oy  = gid >> 2;             // 0..15
    int px  = (gid >> 1) & 1;
    int txg = gid & 1;              // tx in {4*txg .. 4*txg+3}
    int p3  = (oy & 1) * 2 + px;
    int ty  = oy >> 1;
    int y   = 2 * G0 + oy;

    // 4 pixels x 25 weights, loaded once (in flight across the barrier drain);
    // the cg-quad loads identical addresses -> request-merged broadcast.
    float w4[4][25];
    {
        const float* wb2 = Wsm + (((size_t)b * 128 + y) * 128) * 28;
#pragma unroll
        for (int t = 0; t < 4; ++t) {
            int x = 2 * H0 + 2 * (txg * 4 + t) + px;
            const float* wp = wb2 + (size_t)x * 28;
            LOADW(w4[t], wp);
        }
    }
    __syncthreads();

    // phase 3: per (channel, kernel-row): one 8-float window (2 b128) -> 4 pixels x 5 taps
    float acc[4][4];
#pragma unroll
    for (int i = 0; i < 4; ++i)
#pragma unroll
        for (int t = 0; t < 4; ++t) acc[i][t] = 0.f;

    const float* pc0 = P + p3 * 2376 + ty * 12 + txg * 4;
#pragma unroll
    for (int i = 0; i < 4; ++i) {
        const float* pcc = pc0 + (cg + 4 * i) * 148;
#pragma unroll
        for (int i5 = 0; i5 < 5; ++i5) {
            float4 ra = *(const float4*)(pcc + i5 * 12);
            float4 rb = *(const float4*)(pcc + i5 * 12 + 4);
            float rw[8] = {ra.x, ra.y, ra.z, ra.w, rb.x, rb.y, rb.z, rb.w};
#pragma unroll
            for (int t = 0; t < 4; ++t) {
#pragma unroll
                for (int dx = 0; dx < 5; ++dx)
                    acc[i][t] = fmaf(w4[t][i5 * 5 + dx], rw[t + dx], acc[i][t]);
            }
        }
    }

    // stores: 16 scattered dwords/thread; the 4 t-stores of each (c,row) hit the same
    // 64B sector (x = 2t,2t+1,2t+8,2t+9 < 16) -> merged in L2, full sectors to HBM.
    float* ob = out + (((size_t)(b * 256 + c0 + cg) * 128 + y) * 128) + 2 * H0 + 8 * txg + px;
#pragma unroll
    for (int i = 0; i < 4; ++i) {
#pragma unroll
        for (int t = 0; t < 4; ++t)
            ob[(size_t)(4 * i) * 16384 + 2 * t] = acc[i][t];
    }
}

extern "C" void kernel_launch(void* const* d_in, const int* in_sizes, int n_in,
                              void* d_out, int out_size, void* d_ws, size_t ws_size,
                              hipStream_t stream)
{
    const float* X      = (const float*)d_in[0];
    const float* comp_w = (const float*)d_in[1];
    const float* comp_b = (const float*)d_in[2];
    const float* bn1_g  = (const float*)d_in[3];
    const float* bn1_b  = (const float*)d_in[4];
    const float* bn1_m  = (const float*)d_in[5];
    const float* bn1_v  = (const float*)d_in[6];
    const float* enc_w  = (const float*)d_in[7];
    const float* enc_b  = (const float*)d_in[8];
    const float* bn2_g  = (const float*)d_in[9];
    const float* bn2_b  = (const float*)d_in[10];
    const float* bn2_m  = (const float*)d_in[11];
    const float* bn2_v  = (const float*)d_in[12];

    float* ws   = (float*)d_ws;
    float* W1wT = ws;                 // 16384
    float* b1f  = ws + 16384;         // 64
    float* encT = ws + 16448;         // 73728
    float* biasT= ws + 90176;         // 128
    float* W1   = ws + 90304;         // 2097152 (8 MB)
    float* Wsm  = ws + 2187456;       // 3670016 (14.7 MB)

    float* outp = (float*)d_out;

    k0_prep<<<1, 256, 0, stream>>>(comp_w, comp_b, bn1_g, bn1_b, bn1_m, bn1_v,
                                   enc_w, enc_b, bn2_g, bn2_b, bn2_m, bn2_v,
                                   W1wT, b1f, encT, biasT);
    k1_conv1<<<512, 256, 0, stream>>>(X, W1wT, b1f, W1);
    k2_conv2<<<512, 512, 0, stream>>>(W1, encT, biasT, Wsm);
    k3_carafe<<<8192, 256, 0, stream>>>(X, Wsm, outp);
}

// Round 2
// 388.854 us; speedup vs baseline: 1.1787x; 1.1787x over previous
//
#include <hip/hip_runtime.h>

#define EPS 1e-5f

// ---------------- K0: fold BN into weights, transpose for s_load ----------------
// R2: parallelized across 64 blocks (was 1 block = single-CU latency serial ~100us).
__global__ void k0_prep(const float* __restrict__ comp_w, const float* __restrict__ comp_b,
                        const float* __restrict__ bn1_g, const float* __restrict__ bn1_b,
                        const float* __restrict__ bn1_m, const float* __restrict__ bn1_v,
                        const float* __restrict__ enc_w, const float* __restrict__ enc_b,
                        const float* __restrict__ bn2_g, const float* __restrict__ bn2_b,
                        const float* __restrict__ bn2_m, const float* __restrict__ bn2_v,
                        float* __restrict__ W1wT, float* __restrict__ b1f,
                        float* __restrict__ encT, float* __restrict__ biasT)
{
    int gtid = blockIdx.x * 256 + threadIdx.x;
    int gstride = gridDim.x * 256;
    for (int i = gtid; i < 256 * 64; i += gstride) {
        int cin = i >> 6, co = i & 63;
        float s = bn1_g[co] * rsqrtf(bn1_v[co] + EPS);
        W1wT[i] = comp_w[co * 256 + cin] * s;
    }
    for (int i = gtid; i < 64; i += gstride) {
        float s = bn1_g[i] * rsqrtf(bn1_v[i] + EPS);
        b1f[i] = (comp_b[i] - bn1_m[i]) * s + bn1_b[i];
    }
    for (int i = gtid; i < 4 * 64 * 9 * 32; i += gstride) {
        int k = i & 31;
        int rest = i >> 5;
        int dxy = rest % 9;
        int tmp = rest / 9;
        int cin = tmp & 63, p = tmp >> 6;
        float v = 0.f;
        if (k < 25) {
            int ko = 4 * k + p;
            float s = bn2_g[ko] * rsqrtf(bn2_v[ko] + EPS);
            v = enc_w[(ko * 64 + cin) * 9 + dxy] * s;
        }
        encT[i] = v;
    }
    for (int i = gtid; i < 4 * 32; i += gstride) {
        int p = i >> 5, k = i & 31;
        float v = 0.f;
        if (k < 25) {
            int ko = 4 * k + p;
            float s = bn2_g[ko] * rsqrtf(bn2_v[ko] + EPS);
            v = (enc_b[ko] - bn2_m[ko]) * s + bn2_b[ko];
        }
        biasT[i] = v;
    }
}

// ---------------- K1: conv1x1 + bias + ReLU ----------------
// R2: cog 4->8 (grid 1024, 4 blocks/CU, 16 waves/CU) for latency hiding; was 8 waves/CU.
// cog slowest, stride-128 grid -> all 8 cog-sharers of an X tile land on the same XCD L2.
__global__ __launch_bounds__(256, 4) void k1_conv1(const float* __restrict__ X,
                                                   const float* __restrict__ W1wT,
                                                   const float* __restrict__ b1f,
                                                   float* __restrict__ W1)
{
    int blk = blockIdx.x;
    int cog = blk >> 7;            // 0..7
    int b   = (blk >> 4) & 7;
    int pt  = blk & 15;
    int pos = pt * 256 + threadIdx.x;
    const float* xp = X + (size_t)b * 256 * 4096 + pos;
    const float* wp = W1wT + cog * 8;       // uniform -> s_load
    float acc[8];
#pragma unroll
    for (int k = 0; k < 8; ++k) acc[k] = 0.f;
#pragma unroll 8
    for (int cin = 0; cin < 256; ++cin) {
        float x = xp[(size_t)cin * 4096];
        const float* w = wp + cin * 64;
#pragma unroll
        for (int k = 0; k < 8; ++k) acc[k] = fmaf(w[k], x, acc[k]);
    }
    float* op = W1 + ((size_t)b * 64 + cog * 8) * 4096 + pos;
#pragma unroll
    for (int k = 0; k < 8; ++k) {
        float v = acc[k] + b1f[cog * 8 + k];
        op[(size_t)k * 4096] = fmaxf(v, 0.f);
    }
}

// ---------------- K2: conv3x3 + BN + pixel-shuffle + softmax(25) ----------------
// 512 threads = 8 waves = p(4) x cinHalf(2). Halves the 576-long s_load chain and
// doubles resident waves (R2: 8 waves/CU latency-bound). Partial accs combined in LDS.
__global__ __launch_bounds__(512, 4) void k2_conv2(const float* __restrict__ W1,
                                                   const float* __restrict__ encT,
                                                   const float* __restrict__ biasT,
                                                   float* __restrict__ Wsm)
{
    __shared__ float tile[6400];    // 64 cin x 10 x 10, 25.6 KB
    __shared__ float red[6400];     // [p][lane][25] partials, 25.6 KB (stride 25 -> 2-way)
    int blk = blockIdx.x;
    int tc = blk & 7;
    int tr = (blk >> 3) & 7;
    int b  = blk >> 6;
    int tid = threadIdx.x;

    const float* wb = W1 + (size_t)b * 64 * 4096;
    for (int i = tid; i < 6400; i += 512) {
        int cin = i / 100;
        int rr = (i - cin * 100) / 10;
        int cc = i - cin * 100 - rr * 10;
        int r = tr * 8 - 1 + rr, c = tc * 8 - 1 + cc;
        float v = 0.f;
        if (r >= 0 && r < 64 && c >= 0 && c < 64) v = wb[cin * 4096 + r * 64 + c];
        tile[i] = v;
    }
    __syncthreads();

    int w    = tid >> 6;
    int p    = __builtin_amdgcn_readfirstlane(w & 3);
    int cinh = __builtin_amdgcn_readfirstlane(w >> 2);
    int lane = tid & 63;
    int pr = lane >> 3, pc = lane & 7;
    const float* wt = encT + (size_t)(p * 576 + cinh * 288) * 32;  // [p][cin][dxy][32]
    const float* tp = tile + cinh * 32 * 100;
    float acc[25];
#pragma unroll
    for (int k = 0; k < 25; ++k) acc[k] = 0.f;

    for (int cin = 0; cin < 32; ++cin) {
#pragma unroll
        for (int dy = 0; dy < 3; ++dy) {
#pragma unroll
            for (int dx = 0; dx < 3; ++dx) {
                float v = tp[cin * 100 + (pr + dy) * 10 + (pc + dx)];
                const float* wv = wt + (cin * 9 + dy * 3 + dx) * 32;  // uniform -> s_load
#pragma unroll
                for (int k = 0; k < 25; ++k) acc[k] = fmaf(wv[k], v, acc[k]);
            }
        }
    }

    if (cinh == 0) {
        float* rp = red + (p * 64 + lane) * 25;
#pragma unroll
        for (int k = 0; k < 25; ++k) rp[k] = acc[k];
    }
    __syncthreads();
    if (cinh == 1) {
        const float* rp = red + (p * 64 + lane) * 25;
#pragma unroll
        for (int k = 0; k < 25; ++k) acc[k] += rp[k];

        const float* bp = biasT + p * 32;
        float mx = -1e30f;
#pragma unroll
        for (int k = 0; k < 25; ++k) { acc[k] += bp[k]; mx = fmaxf(mx, acc[k]); }
        float sum = 0.f;
#pragma unroll
        for (int k = 0; k < 25; ++k) { acc[k] = __expf(acc[k] - mx); sum += acc[k]; }
        float rs = 1.f / sum;
#pragma unroll
        for (int k = 0; k < 25; ++k) acc[k] *= rs;

        int py = p >> 1, px = p & 1;
        int y = (tr * 8 + pr) * 2 + py, x = (tc * 8 + pc) * 2 + px;
        float* op = Wsm + (((size_t)b * 128 + y) * 128 + x) * 28;
#pragma unroll
        for (int k = 0; k < 6; ++k) {
            float4 v = make_float4(acc[k*4], acc[k*4+1], acc[k*4+2], acc[k*4+3]);
            *(float4*)(op + k * 4) = v;
        }
        op[24] = acc[24];
    }
}

// ---------------- K3: bilinear parity planes + 5x5 weighted reassembly ----------------
// Thread owns 4 x-adjacent same-parity pixels x 4 channels: 8-float window (2 b128)
// feeds 4 pixels x 5 exact taps -> 40 b128 + 400 FMA per thread.
// R2 bank fix: c-stride 148->152 (24*cg mod 32 -> {0,24,16,8}), plane 2376->2440
// (8*p3 -> {0,8,16,24}). Every consecutive-8-lane issue group (sub pair x cg quad)
// now covers all 8 bank groups with distinct residues -> conflict-free phase-3 reads.
// LDS 54,144 B -> still 3 blocks/CU (3 x 54,272 = 162,816 <= 163,840).
#define LOADW(W, q) do { \
    float4 t0 = *(const float4*)(q);       float4 t1 = *(const float4*)((q) + 4);  \
    float4 t2 = *(const float4*)((q) + 8); float4 t3 = *(const float4*)((q) + 12); \
    float4 t4 = *(const float4*)((q) + 16); float4 t5 = *(const float4*)((q) + 20); \
    W[0]=t0.x; W[1]=t0.y; W[2]=t0.z; W[3]=t0.w; \
    W[4]=t1.x; W[5]=t1.y; W[6]=t1.z; W[7]=t1.w; \
    W[8]=t2.x; W[9]=t2.y; W[10]=t2.z; W[11]=t2.w; \
    W[12]=t3.x; W[13]=t3.y; W[14]=t3.z; W[15]=t3.w; \
    W[16]=t4.x; W[17]=t4.y; W[18]=t4.z; W[19]=t4.w; \
    W[20]=t5.x; W[21]=t5.y; W[22]=t5.z; W[23]=t5.w; \
    W[24]=(q)[24]; } while (0)

#define P_CSTR  152
#define P_PSTR  2440

__global__ __launch_bounds__(256, 3) void k3_carafe(const float* __restrict__ X,
                                                    const float* __restrict__ Wsm,
                                                    float* __restrict__ out)
{
    __shared__ __align__(16) float Bx[16 * 236];      // 15.1 KB
    __shared__ __align__(16) float P[4 * P_PSTR];     // 39.0 KB

    int blk = blockIdx.x;
    int chunk = blk >> 9;           // slowest: all CUs on same chunk; tile-sharers same XCD
    int b     = (blk >> 6) & 7;
    int tile  = blk & 63;
    int G0 = (tile >> 3) * 8;
    int H0 = (tile & 7) * 8;
    int c0 = chunk * 16;
    int tid = threadIdx.x;

    // phase 1: X tile [c][14][14] in 16-wide rows, clamp folded (== jax resize edges)
    {
        const float* xb = X + (size_t)(b * 256 + c0) * 4096;
        for (int i = tid; i < 16 * 196; i += 256) {
            int c = i / 196;
            int r = (i - c * 196) / 14;
            int s = i - c * 196 - r * 14;
            int gr = G0 - 3 + r; gr = gr < 0 ? 0 : (gr > 63 ? 63 : gr);
            int gc = H0 - 3 + s; gc = gc < 0 ? 0 : (gc > 63 ? 63 : gc);
            Bx[c * 236 + r * 16 + s] = xb[(size_t)c * 4096 + gr * 64 + gc];
        }
    }
    __syncthreads();

    // phase 2: parity-plane rows; lane map c=(tid>>2)&15, tl=tid&3 -> write residues
    // spread over banks. pp wave-uniform (no divergence).
    {
        int c2 = (tid >> 2) & 15;
        int tl = tid & 3;
        int pp = __builtin_amdgcn_readfirstlane(tid >> 6);
        int py2 = pp >> 1, px2 = pp & 1;
        float wy0 = py2 ? 0.75f : 0.25f, wy1 = 1.f - wy0;
        float wx0 = px2 ? 0.75f : 0.25f, wx1 = 1.f - wx0;
#pragma unroll
        for (int k = 0; k < 3; ++k) {
            int t = tl + 4 * k;
            bool row_ok = (unsigned)(G0 - 2 + t) < 64u;
            const float* rp0 = Bx + c2 * 236 + (t + py2) * 16;
            float x0[16], x1[16];
#pragma unroll
            for (int q = 0; q < 4; ++q) {
                float4 a = *(const float4*)(rp0 + q * 4);
                float4 e = *(const float4*)(rp0 + 16 + q * 4);
                x0[q*4+0]=a.x; x0[q*4+1]=a.y; x0[q*4+2]=a.z; x0[q*4+3]=a.w;
                x1[q*4+0]=e.x; x1[q*4+1]=e.y; x1[q*4+2]=e.z; x1[q*4+3]=e.w;
            }
            float v[12];
            if (px2 == 0) {
#pragma unroll
                for (int s = 0; s < 12; ++s)
                    v[s] = wy0 * (wx0 * x0[s] + wx1 * x0[s+1]) + wy1 * (wx0 * x1[s] + wx1 * x1[s+1]);
            } else {
#pragma unroll
                for (int s = 0; s < 12; ++s)
                    v[s] = wy0 * (wx0 * x0[s+1] + wx1 * x0[s+2]) + wy1 * (wx0 * x1[s+1] + wx1 * x1[s+2]);
            }
#pragma unroll
            for (int s = 0; s < 12; ++s) {
                bool ok = row_ok && ((unsigned)(H0 - 2 + s) < 64u);
                v[s] = ok ? v[s] : 0.f;
            }
            float* dst = P + pp * P_PSTR + c2 * P_CSTR + t * 12;
#pragma unroll
            for (int q = 0; q < 3; ++q)
                *(float4*)(dst + q * 4) = make_float4(v[q*4], v[q*4+1], v[q*4+2], v[q*4+3]);
        }
    }

    // thread -> 4 output pixels (same row/parity, tx group of 4) x 4 channels
    int cg  = tid & 3;              // channel group: c = cg + 4*i
    int gid = tid >> 2;
    int oy  = gid >> 2;             // 0..15
    int px  = (gid >> 1) & 1;
    int txg = gid & 1;              // tx in {4*txg .. 4*txg+3}
    int p3  = (oy & 1) * 2 + px;
    int ty  = oy >> 1;
    int y   = 2 * G0 + oy;

    // 4 pixels x 25 weights, loaded once (in flight across the barrier drain);
    // the cg-quad loads identical addresses -> request-merged broadcast.
    float w4[4][25];
    {
        const float* wb2 = Wsm + (((size_t)b * 128 + y) * 128) * 28;
#pragma unroll
        for (int t = 0; t < 4; ++t) {
            int x = 2 * H0 + 2 * (txg * 4 + t) + px;
            const float* wp = wb2 + (size_t)x * 28;
            LOADW(w4[t], wp);
        }
    }
    __syncthreads();

    // phase 3: per (channel, kernel-row): one 8-float window (2 b128) -> 4 pixels x 5 taps
    float acc[4][4];
#pragma unroll
    for (int i = 0; i < 4; ++i)
#pragma unroll
        for (int t = 0; t < 4; ++t) acc[i][t] = 0.f;

    const float* pc0 = P + p3 * P_PSTR + ty * 12 + txg * 4;
#pragma unroll
    for (int i = 0; i < 4; ++i) {
        const float* pcc = pc0 + (cg + 4 * i) * P_CSTR;
#pragma unroll
        for (int i5 = 0; i5 < 5; ++i5) {
            float4 ra = *(const float4*)(pcc + i5 * 12);
            float4 rb = *(const float4*)(pcc + i5 * 12 + 4);
            float rw[8] = {ra.x, ra.y, ra.z, ra.w, rb.x, rb.y, rb.z, rb.w};
#pragma unroll
            for (int t = 0; t < 4; ++t) {
#pragma unroll
                for (int dx = 0; dx < 5; ++dx)
                    acc[i][t] = fmaf(w4[t][i5 * 5 + dx], rw[t + dx], acc[i][t]);
            }
        }
    }

    // stores: 16 scattered dwords/thread; the 4 t-stores of each (c,row) hit the same
    // 64B sector (x = 2t,2t+1,2t+8,2t+9 < 16) -> merged in L2, full sectors to HBM.
    float* ob = out + (((size_t)(b * 256 + c0 + cg) * 128 + y) * 128) + 2 * H0 + 8 * txg + px;
#pragma unroll
    for (int i = 0; i < 4; ++i) {
#pragma unroll
        for (int t = 0; t < 4; ++t)
            ob[(size_t)(4 * i) * 16384 + 2 * t] = acc[i][t];
    }
}

extern "C" void kernel_launch(void* const* d_in, const int* in_sizes, int n_in,
                              void* d_out, int out_size, void* d_ws, size_t ws_size,
                              hipStream_t stream)
{
    const float* X      = (const float*)d_in[0];
    const float* comp_w = (const float*)d_in[1];
    const float* comp_b = (const float*)d_in[2];
    const float* bn1_g  = (const float*)d_in[3];
    const float* bn1_b  = (const float*)d_in[4];
    const float* bn1_m  = (const float*)d_in[5];
    const float* bn1_v  = (const float*)d_in[6];
    const float* enc_w  = (const float*)d_in[7];
    const float* enc_b  = (const float*)d_in[8];
    const float* bn2_g  = (const float*)d_in[9];
    const float* bn2_b  = (const float*)d_in[10];
    const float* bn2_m  = (const float*)d_in[11];
    const float* bn2_v  = (const float*)d_in[12];

    float* ws   = (float*)d_ws;
    float* W1wT = ws;                 // 16384
    float* b1f  = ws + 16384;         // 64
    float* encT = ws + 16448;         // 73728
    float* biasT= ws + 90176;         // 128
    float* W1   = ws + 90304;         // 2097152 (8 MB)
    float* Wsm  = ws + 2187456;       // 3670016 (14.7 MB)

    float* outp = (float*)d_out;

    k0_prep<<<64, 256, 0, stream>>>(comp_w, comp_b, bn1_g, bn1_b, bn1_m, bn1_v,
                                    enc_w, enc_b, bn2_g, bn2_b, bn2_m, bn2_v,
                                    W1wT, b1f, encT, biasT);
    k1_conv1<<<1024, 256, 0, stream>>>(X, W1wT, b1f, W1);
    k2_conv2<<<512, 512, 0, stream>>>(W1, encT, biasT, Wsm);
    k3_carafe<<<8192, 256, 0, stream>>>(X, Wsm, outp);
}

// Round 4
// 375.202 us; speedup vs baseline: 1.2216x; 1.0364x over previous
//
#include <hip/hip_runtime.h>

#define EPS 1e-5f

// ---------------- K0: fold BN into weights, transpose for s_load ----------------
// Parallelized across 64 blocks (R2: was 1 block = single-CU latency serial ~100us).
__global__ void k0_prep(const float* __restrict__ comp_w, const float* __restrict__ comp_b,
                        const float* __restrict__ bn1_g, const float* __restrict__ bn1_b,
                        const float* __restrict__ bn1_m, const float* __restrict__ bn1_v,
                        const float* __restrict__ enc_w, const float* __restrict__ enc_b,
                        const float* __restrict__ bn2_g, const float* __restrict__ bn2_b,
                        const float* __restrict__ bn2_m, const float* __restrict__ bn2_v,
                        float* __restrict__ W1wT, float* __restrict__ b1f,
                        float* __restrict__ encT, float* __restrict__ biasT)
{
    int gtid = blockIdx.x * 256 + threadIdx.x;
    int gstride = gridDim.x * 256;
    for (int i = gtid; i < 256 * 64; i += gstride) {
        int cin = i >> 6, co = i & 63;
        float s = bn1_g[co] * rsqrtf(bn1_v[co] + EPS);
        W1wT[i] = comp_w[co * 256 + cin] * s;
    }
    for (int i = gtid; i < 64; i += gstride) {
        float s = bn1_g[i] * rsqrtf(bn1_v[i] + EPS);
        b1f[i] = (comp_b[i] - bn1_m[i]) * s + bn1_b[i];
    }
    for (int i = gtid; i < 4 * 64 * 9 * 32; i += gstride) {
        int k = i & 31;
        int rest = i >> 5;
        int dxy = rest % 9;
        int tmp = rest / 9;
        int cin = tmp & 63, p = tmp >> 6;
        float v = 0.f;
        if (k < 25) {
            int ko = 4 * k + p;
            float s = bn2_g[ko] * rsqrtf(bn2_v[ko] + EPS);
            v = enc_w[(ko * 64 + cin) * 9 + dxy] * s;
        }
        encT[i] = v;
    }
    for (int i = gtid; i < 4 * 32; i += gstride) {
        int p = i >> 5, k = i & 31;
        float v = 0.f;
        if (k < 25) {
            int ko = 4 * k + p;
            float s = bn2_g[ko] * rsqrtf(bn2_v[ko] + EPS);
            v = (enc_b[ko] - bn2_m[ko]) * s + bn2_b[ko];
        }
        biasT[i] = v;
    }
}

// ---------------- K1: conv1x1 + bias + ReLU ----------------
// cog(8) slowest, stride-128 grid -> all 8 cog-sharers of an X tile on the same XCD L2.
// 4 blocks/CU, 16 waves/CU.
__global__ __launch_bounds__(256, 4) void k1_conv1(const float* __restrict__ X,
                                                   const float* __restrict__ W1wT,
                                                   const float* __restrict__ b1f,
                                                   float* __restrict__ W1)
{
    int blk = blockIdx.x;
    int cog = blk >> 7;            // 0..7
    int b   = (blk >> 4) & 7;
    int pt  = blk & 15;
    int pos = pt * 256 + threadIdx.x;
    const float* xp = X + (size_t)b * 256 * 4096 + pos;
    const float* wp = W1wT + cog * 8;       // uniform -> s_load
    float acc[8];
#pragma unroll
    for (int k = 0; k < 8; ++k) acc[k] = 0.f;
#pragma unroll 8
    for (int cin = 0; cin < 256; ++cin) {
        float x = xp[(size_t)cin * 4096];
        const float* w = wp + cin * 64;
#pragma unroll
        for (int k = 0; k < 8; ++k) acc[k] = fmaf(w[k], x, acc[k]);
    }
    float* op = W1 + ((size_t)b * 64 + cog * 8) * 4096 + pos;
#pragma unroll
    for (int k = 0; k < 8; ++k) {
        float v = acc[k] + b1f[cog * 8 + k];
        op[(size_t)k * 4096] = fmaxf(v, 0.f);
    }
}

// ---------------- K2: conv3x3 + BN + pixel-shuffle + softmax(25) ----------------
// 512 threads = 8 waves = p(4) x cinHalf(2). Partial accs combined in LDS.
__global__ __launch_bounds__(512, 4) void k2_conv2(const float* __restrict__ W1,
                                                   const float* __restrict__ encT,
                                                   const float* __restrict__ biasT,
                                                   float* __restrict__ Wsm)
{
    __shared__ float tile[6400];    // 64 cin x 10 x 10, 25.6 KB
    __shared__ float red[6400];     // [p][lane][25] partials, 25.6 KB (stride 25 -> 2-way)
    int blk = blockIdx.x;
    int tc = blk & 7;
    int tr = (blk >> 3) & 7;
    int b  = blk >> 6;
    int tid = threadIdx.x;

    const float* wb = W1 + (size_t)b * 64 * 4096;
    for (int i = tid; i < 6400; i += 512) {
        int cin = i / 100;
        int rr = (i - cin * 100) / 10;
        int cc = i - cin * 100 - rr * 10;
        int r = tr * 8 - 1 + rr, c = tc * 8 - 1 + cc;
        float v = 0.f;
        if (r >= 0 && r < 64 && c >= 0 && c < 64) v = wb[cin * 4096 + r * 64 + c];
        tile[i] = v;
    }
    __syncthreads();

    int w    = tid >> 6;
    int p    = __builtin_amdgcn_readfirstlane(w & 3);
    int cinh = __builtin_amdgcn_readfirstlane(w >> 2);
    int lane = tid & 63;
    int pr = lane >> 3, pc = lane & 7;
    const float* wt = encT + (size_t)(p * 576 + cinh * 288) * 32;  // [p][cin][dxy][32]
    const float* tp = tile + cinh * 32 * 100;
    float acc[25];
#pragma unroll
    for (int k = 0; k < 25; ++k) acc[k] = 0.f;

    for (int cin = 0; cin < 32; ++cin) {
#pragma unroll
        for (int dy = 0; dy < 3; ++dy) {
#pragma unroll
            for (int dx = 0; dx < 3; ++dx) {
                float v = tp[cin * 100 + (pr + dy) * 10 + (pc + dx)];
                const float* wv = wt + (cin * 9 + dy * 3 + dx) * 32;  // uniform -> s_load
#pragma unroll
                for (int k = 0; k < 25; ++k) acc[k] = fmaf(wv[k], v, acc[k]);
            }
        }
    }

    if (cinh == 0) {
        float* rp = red + (p * 64 + lane) * 25;
#pragma unroll
        for (int k = 0; k < 25; ++k) rp[k] = acc[k];
    }
    __syncthreads();
    if (cinh == 1) {
        const float* rp = red + (p * 64 + lane) * 25;
#pragma unroll
        for (int k = 0; k < 25; ++k) acc[k] += rp[k];

        const float* bp = biasT + p * 32;
        float mx = -1e30f;
#pragma unroll
        for (int k = 0; k < 25; ++k) { acc[k] += bp[k]; mx = fmaxf(mx, acc[k]); }
        float sum = 0.f;
#pragma unroll
        for (int k = 0; k < 25; ++k) { acc[k] = __expf(acc[k] - mx); sum += acc[k]; }
        float rs = 1.f / sum;
#pragma unroll
        for (int k = 0; k < 25; ++k) acc[k] *= rs;

        int py = p >> 1, px = p & 1;
        int y = (tr * 8 + pr) * 2 + py, x = (tc * 8 + pc) * 2 + px;
        float* op = Wsm + (((size_t)b * 128 + y) * 128 + x) * 28;
#pragma unroll
        for (int k = 0; k < 6; ++k) {
            float4 v = make_float4(acc[k*4], acc[k*4+1], acc[k*4+2], acc[k*4+3]);
            *(float4*)(op + k * 4) = v;
        }
        op[24] = acc[24];
    }
}

// ---------------- K3: bilinear parity planes + 5x5 weighted reassembly ----------------
// R4: fix R3's correctness bug. R3's additive Bx stagger (16r + 8*((r>>1)&1)) made
// 14-word rows r=3,7,11 overlap rows r+1 (e.g. [56,70) vs [64,..)) -> garbage.
// Fix: XOR stagger in the ROW-LOCAL coordinate: phys = c*236 + 16r + (s ^ x_r),
// x_r = 8*((r>>1)&1). s in [0,14) maps bijectively into [0,16) -> no spillover.
// Bank effect preserved: rows mod 4 start banks {0,16,8,24}; odd c2 adds 12.
// P kept compact + XOR-swizzled (verified bijective: channel boundaries fall at
// 32-block offsets 0/16; split-block XOR pairs are only (0,8) and (16,24), both safe).
// LDS total 51,968B -> 3 blocks/CU (R2 lesson: 2-KiB granularity cliff at ~54KB).
#define LOADW(W, q) do { \
    float4 t0 = *(const float4*)(q);       float4 t1 = *(const float4*)((q) + 4);  \
    float4 t2 = *(const float4*)((q) + 8); float4 t3 = *(const float4*)((q) + 12); \
    float4 t4 = *(const float4*)((q) + 16); float4 t5 = *(const float4*)((q) + 20); \
    W[0]=t0.x; W[1]=t0.y; W[2]=t0.z; W[3]=t0.w; \
    W[4]=t1.x; W[5]=t1.y; W[6]=t1.z; W[7]=t1.w; \
    W[8]=t2.x; W[9]=t2.y; W[10]=t2.z; W[11]=t2.w; \
    W[12]=t3.x; W[13]=t3.y; W[14]=t3.z; W[15]=t3.w; \
    W[16]=t4.x; W[17]=t4.y; W[18]=t4.z; W[19]=t4.w; \
    W[20]=t5.x; W[21]=t5.y; W[22]=t5.z; W[23]=t5.w; \
    W[24]=(q)[24]; } while (0)

#define P_CSTR  144
#define P_PSTR  2304
#define BX_XOR(r) ((((r) >> 1) & 1) << 3)

__global__ __launch_bounds__(256, 3) void k3_carafe(const float* __restrict__ X,
                                                    const float* __restrict__ Wsm,
                                                    float* __restrict__ out)
{
    __shared__ __align__(16) float Bx[16 * 236];      // 15,104 B
    __shared__ __align__(16) float P[4 * P_PSTR];     // 36,864 B  (total 51,968)

    int blk = blockIdx.x;
    int chunk = blk >> 9;           // slowest: all CUs on same chunk; tile-sharers same XCD
    int b     = (blk >> 6) & 7;
    int tile  = blk & 63;
    int G0 = (tile >> 3) * 8;
    int H0 = (tile & 7) * 8;
    int c0 = chunk * 16;
    int tid = threadIdx.x;

    // phase 1: X tile [c][14 rows][14 cols], row-local XOR stagger, clamp folded
    {
        const float* xb = X + (size_t)(b * 256 + c0) * 4096;
        for (int i = tid; i < 16 * 196; i += 256) {
            int c = i / 196;
            int r = (i - c * 196) / 14;
            int s = i - c * 196 - r * 14;
            int gr = G0 - 3 + r; gr = gr < 0 ? 0 : (gr > 63 ? 63 : gr);
            int gc = H0 - 3 + s; gc = gc < 0 ? 0 : (gc > 63 ? 63 : gc);
            Bx[c * 236 + r * 16 + (s ^ BX_XOR(r))] = xb[(size_t)c * 4096 + gr * 64 + gc];
        }
    }
    __syncthreads();

    // phase 2: parity-plane rows; c2=(tid>>2)&15, tl=tid&3. pp wave-uniform.
    {
        int c2 = (tid >> 2) & 15;
        int tl = tid & 3;
        int pp = __builtin_amdgcn_readfirstlane(tid >> 6);
        int py2 = pp >> 1, px2 = pp & 1;
        float wy0 = py2 ? 0.75f : 0.25f, wy1 = 1.f - wy0;
        float wx0 = px2 ? 0.75f : 0.25f, wx1 = 1.f - wx0;
        int cxor2 = (c2 & 3) << 3;
#pragma unroll
        for (int k = 0; k < 3; ++k) {
            int t = tl + 4 * k;
            bool row_ok = (unsigned)(G0 - 2 + t) < 64u;
            int row0 = t + py2, row1 = row0 + 1;
            int x0r = BX_XOR(row0), x1r = BX_XOR(row1);
            const float* rp0 = Bx + c2 * 236 + row0 * 16;
            const float* rp1 = Bx + c2 * 236 + row1 * 16;
            float x0[16], x1[16];
#pragma unroll
            for (int q = 0; q < 4; ++q) {
                float4 a = *(const float4*)(rp0 + (4 * q ^ x0r));
                float4 e = *(const float4*)(rp1 + (4 * q ^ x1r));
                x0[q*4+0]=a.x; x0[q*4+1]=a.y; x0[q*4+2]=a.z; x0[q*4+3]=a.w;
                x1[q*4+0]=e.x; x1[q*4+1]=e.y; x1[q*4+2]=e.z; x1[q*4+3]=e.w;
            }
            float v[12];
            if (px2 == 0) {
#pragma unroll
                for (int s = 0; s < 12; ++s)
                    v[s] = wy0 * (wx0 * x0[s] + wx1 * x0[s+1]) + wy1 * (wx0 * x1[s] + wx1 * x1[s+1]);
            } else {
#pragma unroll
                for (int s = 0; s < 12; ++s)
                    v[s] = wy0 * (wx0 * x0[s+1] + wx1 * x0[s+2]) + wy1 * (wx0 * x1[s+1] + wx1 * x1[s+2]);
            }
#pragma unroll
            for (int s = 0; s < 12; ++s) {
                bool ok = row_ok && ((unsigned)(H0 - 2 + s) < 64u);
                v[s] = ok ? v[s] : 0.f;
            }
            int dbase = pp * P_PSTR + c2 * P_CSTR + t * 12;
#pragma unroll
            for (int q = 0; q < 3; ++q) {
                int wq = (dbase + 4 * q) ^ cxor2;
                *(float4*)(P + wq) = make_float4(v[q*4], v[q*4+1], v[q*4+2], v[q*4+3]);
            }
        }
    }

    // thread -> 4 output pixels (same row/parity, tx group of 4) x 4 channels
    int cg  = tid & 3;              // channel group: c = cg + 4*i
    int gid = tid >> 2;
    int oy  = gid >> 2;             // 0..15
    int px  = (gid >> 1) & 1;
    int txg = gid & 1;              // tx in {4*txg .. 4*txg+3}
    int p3  = (oy & 1) * 2 + px;
    int ty  = oy >> 1;
    int y   = 2 * G0 + oy;

    // 4 pixels x 25 weights, loaded once (in flight across the barrier drain);
    // the cg-quad loads identical addresses -> request-merged broadcast.
    float w4[4][25];
    {
        const float* wb2 = Wsm + (((size_t)b * 128 + y) * 128) * 28;
#pragma unroll
        for (int t = 0; t < 4; ++t) {
            int x = 2 * H0 + 2 * (txg * 4 + t) + px;
            const float* wp = wb2 + (size_t)x * 28;
            LOADW(w4[t], wp);
        }
    }
    __syncthreads();

    // phase 3: per (channel, kernel-row): one 8-float window (2 b128) -> 4 pixels x 5 taps
    float acc[4][4];
#pragma unroll
    for (int i = 0; i < 4; ++i)
#pragma unroll
        for (int t = 0; t < 4; ++t) acc[i][t] = 0.f;

    int cxor = cg << 3;
    int rbase = p3 * P_PSTR + ty * 12 + txg * 4;
#pragma unroll
    for (int i = 0; i < 4; ++i) {
        int cw = rbase + (cg + 4 * i) * P_CSTR;
#pragma unroll
        for (int i5 = 0; i5 < 5; ++i5) {
            int wa = (cw + i5 * 12) ^ cxor;
            int wb = (cw + i5 * 12 + 4) ^ cxor;
            float4 ra = *(const float4*)(P + wa);
            float4 rb = *(const float4*)(P + wb);
            float rw[8] = {ra.x, ra.y, ra.z, ra.w, rb.x, rb.y, rb.z, rb.w};
#pragma unroll
            for (int t = 0; t < 4; ++t) {
#pragma unroll
                for (int dx = 0; dx < 5; ++dx)
                    acc[i][t] = fmaf(w4[t][i5 * 5 + dx], rw[t + dx], acc[i][t]);
            }
        }
    }

    // stores: 16 scattered dwords/thread; the 4 t-stores of each (c,row) hit the same
    // 64B sector -> merged in L2, full sectors to HBM (WRITE_SIZE == 128 MB confirmed).
    float* ob = out + (((size_t)(b * 256 + c0 + cg) * 128 + y) * 128) + 2 * H0 + 8 * txg + px;
#pragma unroll
    for (int i = 0; i < 4; ++i) {
#pragma unroll
        for (int t = 0; t < 4; ++t)
            ob[(size_t)(4 * i) * 16384 + 2 * t] = acc[i][t];
    }
}

extern "C" void kernel_launch(void* const* d_in, const int* in_sizes, int n_in,
                              void* d_out, int out_size, void* d_ws, size_t ws_size,
                              hipStream_t stream)
{
    const float* X      = (const float*)d_in[0];
    const float* comp_w = (const float*)d_in[1];
    const float* comp_b = (const float*)d_in[2];
    const float* bn1_g  = (const float*)d_in[3];
    const float* bn1_b  = (const float*)d_in[4];
    const float* bn1_m  = (const float*)d_in[5];
    const float* bn1_v  = (const float*)d_in[6];
    const float* enc_w  = (const float*)d_in[7];
    const float* enc_b  = (const float*)d_in[8];
    const float* bn2_g  = (const float*)d_in[9];
    const float* bn2_b  = (const float*)d_in[10];
    const float* bn2_m  = (const float*)d_in[11];
    const float* bn2_v  = (const float*)d_in[12];

    float* ws   = (float*)d_ws;
    float* W1wT = ws;                 // 16384
    float* b1f  = ws + 16384;         // 64
    float* encT = ws + 16448;         // 73728
    float* biasT= ws + 90176;         // 128
    float* W1   = ws + 90304;         // 2097152 (8 MB)
    float* Wsm  = ws + 2187456;       // 3670016 (14.7 MB)

    float* outp = (float*)d_out;

    k0_prep<<<64, 256, 0, stream>>>(comp_w, comp_b, bn1_g, bn1_b, bn1_m, bn1_v,
                                    enc_w, enc_b, bn2_g, bn2_b, bn2_m, bn2_v,
                                    W1wT, b1f, encT, biasT);
    k1_conv1<<<1024, 256, 0, stream>>>(X, W1wT, b1f, W1);
    k2_conv2<<<512, 512, 0, stream>>>(W1, encT, biasT, Wsm);
    k3_carafe<<<8192, 256, 0, stream>>>(X, Wsm, outp);
}

// Round 5
// 365.008 us; speedup vs baseline: 1.2557x; 1.0279x over previous
//
#include <hip/hip_runtime.h>

#define EPS 1e-5f

// ---------------- K0: fold BN into weights, transpose for s_load ----------------
// Parallelized across 64 blocks (R2: was 1 block = single-CU latency serial ~100us).
__global__ void k0_prep(const float* __restrict__ comp_w, const float* __restrict__ comp_b,
                        const float* __restrict__ bn1_g, const float* __restrict__ bn1_b,
                        const float* __restrict__ bn1_m, const float* __restrict__ bn1_v,
                        const float* __restrict__ enc_w, const float* __restrict__ enc_b,
                        const float* __restrict__ bn2_g, const float* __restrict__ bn2_b,
                        const float* __restrict__ bn2_m, const float* __restrict__ bn2_v,
                        float* __restrict__ W1wT, float* __restrict__ b1f,
                        float* __restrict__ encT, float* __restrict__ biasT)
{
    int gtid = blockIdx.x * 256 + threadIdx.x;
    int gstride = gridDim.x * 256;
    for (int i = gtid; i < 256 * 64; i += gstride) {
        int cin = i >> 6, co = i & 63;
        float s = bn1_g[co] * rsqrtf(bn1_v[co] + EPS);
        W1wT[i] = comp_w[co * 256 + cin] * s;
    }
    for (int i = gtid; i < 64; i += gstride) {
        float s = bn1_g[i] * rsqrtf(bn1_v[i] + EPS);
        b1f[i] = (comp_b[i] - bn1_m[i]) * s + bn1_b[i];
    }
    for (int i = gtid; i < 4 * 64 * 9 * 32; i += gstride) {
        int k = i & 31;
        int rest = i >> 5;
        int dxy = rest % 9;
        int tmp = rest / 9;
        int cin = tmp & 63, p = tmp >> 6;
        float v = 0.f;
        if (k < 25) {
            int ko = 4 * k + p;
            float s = bn2_g[ko] * rsqrtf(bn2_v[ko] + EPS);
            v = enc_w[(ko * 64 + cin) * 9 + dxy] * s;
        }
        encT[i] = v;
    }
    for (int i = gtid; i < 4 * 32; i += gstride) {
        int p = i >> 5, k = i & 31;
        float v = 0.f;
        if (k < 25) {
            int ko = 4 * k + p;
            float s = bn2_g[ko] * rsqrtf(bn2_v[ko] + EPS);
            v = (enc_b[ko] - bn2_m[ko]) * s + bn2_b[ko];
        }
        biasT[i] = v;
    }
}

// ---------------- K1: conv1x1 + bias + ReLU ----------------
// cog(8) slowest, stride-128 grid -> all 8 cog-sharers of an X tile on the same XCD L2.
// 4 blocks/CU, 16 waves/CU.
__global__ __launch_bounds__(256, 4) void k1_conv1(const float* __restrict__ X,
                                                   const float* __restrict__ W1wT,
                                                   const float* __restrict__ b1f,
                                                   float* __restrict__ W1)
{
    int blk = blockIdx.x;
    int cog = blk >> 7;            // 0..7
    int b   = (blk >> 4) & 7;
    int pt  = blk & 15;
    int pos = pt * 256 + threadIdx.x;
    const float* xp = X + (size_t)b * 256 * 4096 + pos;
    const float* wp = W1wT + cog * 8;       // uniform -> s_load
    float acc[8];
#pragma unroll
    for (int k = 0; k < 8; ++k) acc[k] = 0.f;
#pragma unroll 8
    for (int cin = 0; cin < 256; ++cin) {
        float x = xp[(size_t)cin * 4096];
        const float* w = wp + cin * 64;
#pragma unroll
        for (int k = 0; k < 8; ++k) acc[k] = fmaf(w[k], x, acc[k]);
    }
    float* op = W1 + ((size_t)b * 64 + cog * 8) * 4096 + pos;
#pragma unroll
    for (int k = 0; k < 8; ++k) {
        float v = acc[k] + b1f[cog * 8 + k];
        op[(size_t)k * 4096] = fmaxf(v, 0.f);
    }
}

// ---------------- K2: conv3x3 + BN + pixel-shuffle + softmax(25) ----------------
// 512 threads = 8 waves = p(4) x cinHalf(2). Partial accs combined in LDS.
__global__ __launch_bounds__(512, 4) void k2_conv2(const float* __restrict__ W1,
                                                   const float* __restrict__ encT,
                                                   const float* __restrict__ biasT,
                                                   float* __restrict__ Wsm)
{
    __shared__ float tile[6400];    // 64 cin x 10 x 10, 25.6 KB
    __shared__ float red[6400];     // [p][lane][25] partials, 25.6 KB (stride 25 -> 2-way)
    int blk = blockIdx.x;
    int tc = blk & 7;
    int tr = (blk >> 3) & 7;
    int b  = blk >> 6;
    int tid = threadIdx.x;

    const float* wb = W1 + (size_t)b * 64 * 4096;
    for (int i = tid; i < 6400; i += 512) {
        int cin = i / 100;
        int rr = (i - cin * 100) / 10;
        int cc = i - cin * 100 - rr * 10;
        int r = tr * 8 - 1 + rr, c = tc * 8 - 1 + cc;
        float v = 0.f;
        if (r >= 0 && r < 64 && c >= 0 && c < 64) v = wb[cin * 4096 + r * 64 + c];
        tile[i] = v;
    }
    __syncthreads();

    int w    = tid >> 6;
    int p    = __builtin_amdgcn_readfirstlane(w & 3);
    int cinh = __builtin_amdgcn_readfirstlane(w >> 2);
    int lane = tid & 63;
    int pr = lane >> 3, pc = lane & 7;
    const float* wt = encT + (size_t)(p * 576 + cinh * 288) * 32;  // [p][cin][dxy][32]
    const float* tp = tile + cinh * 32 * 100;
    float acc[25];
#pragma unroll
    for (int k = 0; k < 25; ++k) acc[k] = 0.f;

    for (int cin = 0; cin < 32; ++cin) {
#pragma unroll
        for (int dy = 0; dy < 3; ++dy) {
#pragma unroll
            for (int dx = 0; dx < 3; ++dx) {
                float v = tp[cin * 100 + (pr + dy) * 10 + (pc + dx)];
                const float* wv = wt + (cin * 9 + dy * 3 + dx) * 32;  // uniform -> s_load
#pragma unroll
                for (int k = 0; k < 25; ++k) acc[k] = fmaf(wv[k], v, acc[k]);
            }
        }
    }

    if (cinh == 0) {
        float* rp = red + (p * 64 + lane) * 25;
#pragma unroll
        for (int k = 0; k < 25; ++k) rp[k] = acc[k];
    }
    __syncthreads();
    if (cinh == 1) {
        const float* rp = red + (p * 64 + lane) * 25;
#pragma unroll
        for (int k = 0; k < 25; ++k) acc[k] += rp[k];

        const float* bp = biasT + p * 32;
        float mx = -1e30f;
#pragma unroll
        for (int k = 0; k < 25; ++k) { acc[k] += bp[k]; mx = fmaxf(mx, acc[k]); }
        float sum = 0.f;
#pragma unroll
        for (int k = 0; k < 25; ++k) { acc[k] = __expf(acc[k] - mx); sum += acc[k]; }
        float rs = 1.f / sum;
#pragma unroll
        for (int k = 0; k < 25; ++k) acc[k] *= rs;

        int py = p >> 1, px = p & 1;
        int y = (tr * 8 + pr) * 2 + py, x = (tc * 8 + pc) * 2 + px;
        float* op = Wsm + (((size_t)b * 128 + y) * 128 + x) * 28;
#pragma unroll
        for (int k = 0; k < 6; ++k) {
            float4 v = make_float4(acc[k*4], acc[k*4+1], acc[k*4+2], acc[k*4+3]);
            *(float4*)(op + k * 4) = v;
        }
        op[24] = acc[24];
    }
}

// ---------------- K3: bilinear parity planes + 5x5 weighted reassembly ----------------
// R5: reverted to the MEASURED-BEST layout (R1 bench: 132.5us, 21.25M conflicts,
// 3 blocks/CU, LDS 53,248B): P c-stride 148 / plane 2376, plain Bx rows (stride 236).
// Three rounds of bank-model-driven swizzles all regressed vs this config (R2: 16M
// conflicts but occupancy cliff; R4: 34.9M conflicts — strided-lane-group analysis says
// the XOR put the 4 p3 planes on one bank). Empirical best wins.
// Split into 2 launches (6144 = 12 chunks exact-fit 8 rounds of 768 resident blocks,
// + 2048) purely so k1/k2 surface in the rocprof top-5 — tail waste unchanged.
#define LOADW(W, q) do { \
    float4 t0 = *(const float4*)(q);       float4 t1 = *(const float4*)((q) + 4);  \
    float4 t2 = *(const float4*)((q) + 8); float4 t3 = *(const float4*)((q) + 12); \
    float4 t4 = *(const float4*)((q) + 16); float4 t5 = *(const float4*)((q) + 20); \
    W[0]=t0.x; W[1]=t0.y; W[2]=t0.z; W[3]=t0.w; \
    W[4]=t1.x; W[5]=t1.y; W[6]=t1.z; W[7]=t1.w; \
    W[8]=t2.x; W[9]=t2.y; W[10]=t2.z; W[11]=t2.w; \
    W[12]=t3.x; W[13]=t3.y; W[14]=t3.z; W[15]=t3.w; \
    W[16]=t4.x; W[17]=t4.y; W[18]=t4.z; W[19]=t4.w; \
    W[20]=t5.x; W[21]=t5.y; W[22]=t5.z; W[23]=t5.w; \
    W[24]=(q)[24]; } while (0)

#define P_CSTR  148
#define P_PSTR  2376

__global__ __launch_bounds__(256, 3) void k3_carafe(const float* __restrict__ X,
                                                    const float* __restrict__ Wsm,
                                                    float* __restrict__ out,
                                                    int chunk0)
{
    __shared__ __align__(16) float Bx[16 * 236];      // 15,104 B
    __shared__ __align__(16) float P[4 * P_PSTR];     // 38,016 B  (total 53,120)

    int blk = blockIdx.x;
    int chunk = (blk >> 9) + chunk0; // slowest: all CUs on same chunk; tile-sharers same XCD
    int b     = (blk >> 6) & 7;
    int tile  = blk & 63;
    int G0 = (tile >> 3) * 8;
    int H0 = (tile & 7) * 8;
    int c0 = chunk * 16;
    int tid = threadIdx.x;

    // phase 1: X tile [c][14][14] in 16-wide rows, clamp folded (== jax resize edges)
    {
        const float* xb = X + (size_t)(b * 256 + c0) * 4096;
        for (int i = tid; i < 16 * 196; i += 256) {
            int c = i / 196;
            int r = (i - c * 196) / 14;
            int s = i - c * 196 - r * 14;
            int gr = G0 - 3 + r; gr = gr < 0 ? 0 : (gr > 63 ? 63 : gr);
            int gc = H0 - 3 + s; gc = gc < 0 ? 0 : (gc > 63 ? 63 : gc);
            Bx[c * 236 + r * 16 + s] = xb[(size_t)c * 4096 + gr * 64 + gc];
        }
    }
    __syncthreads();

    // phase 2: parity-plane rows; c2=(tid>>2)&15, tl=tid&3. pp wave-uniform.
    {
        int c2 = (tid >> 2) & 15;
        int tl = tid & 3;
        int pp = __builtin_amdgcn_readfirstlane(tid >> 6);
        int py2 = pp >> 1, px2 = pp & 1;
        float wy0 = py2 ? 0.75f : 0.25f, wy1 = 1.f - wy0;
        float wx0 = px2 ? 0.75f : 0.25f, wx1 = 1.f - wx0;
#pragma unroll
        for (int k = 0; k < 3; ++k) {
            int t = tl + 4 * k;
            bool row_ok = (unsigned)(G0 - 2 + t) < 64u;
            const float* rp0 = Bx + c2 * 236 + (t + py2) * 16;
            float x0[16], x1[16];
#pragma unroll
            for (int q = 0; q < 4; ++q) {
                float4 a = *(const float4*)(rp0 + q * 4);
                float4 e = *(const float4*)(rp0 + 16 + q * 4);
                x0[q*4+0]=a.x; x0[q*4+1]=a.y; x0[q*4+2]=a.z; x0[q*4+3]=a.w;
                x1[q*4+0]=e.x; x1[q*4+1]=e.y; x1[q*4+2]=e.z; x1[q*4+3]=e.w;
            }
            float v[12];
            if (px2 == 0) {
#pragma unroll
                for (int s = 0; s < 12; ++s)
                    v[s] = wy0 * (wx0 * x0[s] + wx1 * x0[s+1]) + wy1 * (wx0 * x1[s] + wx1 * x1[s+1]);
            } else {
#pragma unroll
                for (int s = 0; s < 12; ++s)
                    v[s] = wy0 * (wx0 * x0[s+1] + wx1 * x0[s+2]) + wy1 * (wx0 * x1[s+1] + wx1 * x1[s+2]);
            }
#pragma unroll
            for (int s = 0; s < 12; ++s) {
                bool ok = row_ok && ((unsigned)(H0 - 2 + s) < 64u);
                v[s] = ok ? v[s] : 0.f;
            }
            float* dst = P + pp * P_PSTR + c2 * P_CSTR + t * 12;
#pragma unroll
            for (int q = 0; q < 3; ++q)
                *(float4*)(dst + q * 4) = make_float4(v[q*4], v[q*4+1], v[q*4+2], v[q*4+3]);
        }
    }

    // thread -> 4 output pixels (same row/parity, tx group of 4) x 4 channels
    int cg  = tid & 3;              // channel group: c = cg + 4*i
    int gid = tid >> 2;
    int oy  = gid >> 2;             // 0..15
    int px  = (gid >> 1) & 1;
    int txg = gid & 1;              // tx in {4*txg .. 4*txg+3}
    int p3  = (oy & 1) * 2 + px;
    int ty  = oy >> 1;
    int y   = 2 * G0 + oy;

    // 4 pixels x 25 weights, loaded once (in flight across the barrier drain);
    // the cg-quad loads identical addresses -> request-merged broadcast.
    float w4[4][25];
    {
        const float* wb2 = Wsm + (((size_t)b * 128 + y) * 128) * 28;
#pragma unroll
        for (int t = 0; t < 4; ++t) {
            int x = 2 * H0 + 2 * (txg * 4 + t) + px;
            const float* wp = wb2 + (size_t)x * 28;
            LOADW(w4[t], wp);
        }
    }
    __syncthreads();

    // phase 3: per (channel, kernel-row): one 8-float window (2 b128) -> 4 pixels x 5 taps
    float acc[4][4];
#pragma unroll
    for (int i = 0; i < 4; ++i)
#pragma unroll
        for (int t = 0; t < 4; ++t) acc[i][t] = 0.f;

    const float* pc0 = P + p3 * P_PSTR + ty * 12 + txg * 4;
#pragma unroll
    for (int i = 0; i < 4; ++i) {
        const float* pcc = pc0 + (cg + 4 * i) * P_CSTR;
#pragma unroll
        for (int i5 = 0; i5 < 5; ++i5) {
            float4 ra = *(const float4*)(pcc + i5 * 12);
            float4 rb = *(const float4*)(pcc + i5 * 12 + 4);
            float rw[8] = {ra.x, ra.y, ra.z, ra.w, rb.x, rb.y, rb.z, rb.w};
#pragma unroll
            for (int t = 0; t < 4; ++t) {
#pragma unroll
                for (int dx = 0; dx < 5; ++dx)
                    acc[i][t] = fmaf(w4[t][i5 * 5 + dx], rw[t + dx], acc[i][t]);
            }
        }
    }

    // stores: 16 scattered dwords/thread; the 4 t-stores of each (c,row) hit the same
    // 64B sector -> merged in L2, full sectors to HBM (WRITE_SIZE == 128 MB confirmed).
    float* ob = out + (((size_t)(b * 256 + c0 + cg) * 128 + y) * 128) + 2 * H0 + 8 * txg + px;
#pragma unroll
    for (int i = 0; i < 4; ++i) {
#pragma unroll
        for (int t = 0; t < 4; ++t)
            ob[(size_t)(4 * i) * 16384 + 2 * t] = acc[i][t];
    }
}

extern "C" void kernel_launch(void* const* d_in, const int* in_sizes, int n_in,
                              void* d_out, int out_size, void* d_ws, size_t ws_size,
                              hipStream_t stream)
{
    const float* X      = (const float*)d_in[0];
    const float* comp_w = (const float*)d_in[1];
    const float* comp_b = (const float*)d_in[2];
    const float* bn1_g  = (const float*)d_in[3];
    const float* bn1_b  = (const float*)d_in[4];
    const float* bn1_m  = (const float*)d_in[5];
    const float* bn1_v  = (const float*)d_in[6];
    const float* enc_w  = (const float*)d_in[7];
    const float* enc_b  = (const float*)d_in[8];
    const float* bn2_g  = (const float*)d_in[9];
    const float* bn2_b  = (const float*)d_in[10];
    const float* bn2_m  = (const float*)d_in[11];
    const float* bn2_v  = (const float*)d_in[12];

    float* ws   = (float*)d_ws;
    float* W1wT = ws;                 // 16384
    float* b1f  = ws + 16384;         // 64
    float* encT = ws + 16448;         // 73728
    float* biasT= ws + 90176;         // 128
    float* W1   = ws + 90304;         // 2097152 (8 MB)
    float* Wsm  = ws + 2187456;       // 3670016 (14.7 MB)

    float* outp = (float*)d_out;

    k0_prep<<<64, 256, 0, stream>>>(comp_w, comp_b, bn1_g, bn1_b, bn1_m, bn1_v,
                                    enc_w, enc_b, bn2_g, bn2_b, bn2_m, bn2_v,
                                    W1wT, b1f, encT, biasT);
    k1_conv1<<<1024, 256, 0, stream>>>(X, W1wT, b1f, W1);
    k2_conv2<<<512, 512, 0, stream>>>(W1, encT, biasT, Wsm);
    k3_carafe<<<6144, 256, 0, stream>>>(X, Wsm, outp, 0);
    k3_carafe<<<2048, 256, 0, stream>>>(X, Wsm, outp, 12);
}